// Round 1
// baseline (277.361 us; speedup 1.0000x reference)
//
#include <hip/hip_runtime.h>

#define NROWS 8000
#define DDIM 9
#define NCOL4 (NROWS / 4)   // 2000 float4 per output row

// ---------------------------------------------------------------------------
// Kernel A: per-row reductions. s1/s2 = sum_j ((x-c)/a)^2 ; f = x.w + b
// ---------------------------------------------------------------------------
__global__ __launch_bounds__(256)
void anfis_rows(const float* __restrict__ x,
                const float* __restrict__ a1p, const float* __restrict__ c1p,
                const float* __restrict__ a2p, const float* __restrict__ c2p,
                const float* __restrict__ w_fc1, const float* __restrict__ b_fc1,
                const float* __restrict__ w_fc2, const float* __restrict__ b_fc2,
                float* __restrict__ s1o, float* __restrict__ s2o,
                float* __restrict__ f1o, float* __restrict__ f2o) {
    int r = blockIdx.x * 256 + threadIdx.x;
    if (r >= NROWS) return;
    const float inv_a1 = 1.0f / a1p[0];
    const float c1 = c1p[0];
    const float inv_a2 = 1.0f / a2p[0];
    const float c2 = c2p[0];
    float s1 = 0.f, s2 = 0.f, d1 = 0.f, d2 = 0.f;
#pragma unroll
    for (int j = 0; j < DDIM; ++j) {
        float xv = x[r * DDIM + j];
        float t1 = (xv - c1) * inv_a1;
        float t2 = (xv - c2) * inv_a2;
        s1 += t1 * t1;
        s2 += t2 * t2;
        d1 += xv * w_fc1[j];
        d2 += xv * w_fc2[j];
    }
    s1o[r] = s1;
    s2o[r] = s2;
    f1o[r] = d1 + b_fc1[0];
    f2o[r] = d2 + b_fc2[0];
}

// ---------------------------------------------------------------------------
// Kernel B: single-block cumsum of (s1,s2) over 8000 rows, then
// w1_bar[i] = 1/(1+exp(cs1-cs2)), w2_bar = 1 - w1_bar (computed symmetrically)
// log-space equivalent of cumprod(prod(exp(-t^2))) normalization.
// ---------------------------------------------------------------------------
#define SCAN_T 1024
#define RPT 8   // 1024 * 8 = 8192 >= 8000

__global__ __launch_bounds__(SCAN_T)
void anfis_scan(const float* __restrict__ s1, const float* __restrict__ s2,
                float* __restrict__ w1bo, float* __restrict__ w2bo) {
    __shared__ float sh1[SCAN_T];
    __shared__ float sh2[SCAN_T];
    const int t = threadIdx.x;
    const int r0 = t * RPT;

    float cs1[RPT], cs2[RPT];
    float run1 = 0.f, run2 = 0.f;
#pragma unroll
    for (int k = 0; k < RPT; ++k) {
        int r = r0 + k;
        float v1 = 0.f, v2 = 0.f;
        if (r < NROWS) { v1 = s1[r]; v2 = s2[r]; }
        run1 += v1;
        run2 += v2;
        cs1[k] = run1;
        cs2[k] = run2;
    }
    sh1[t] = run1;
    sh2[t] = run2;
    __syncthreads();
    // Hillis-Steele inclusive scan over thread totals
    for (int off = 1; off < SCAN_T; off <<= 1) {
        float v1 = 0.f, v2 = 0.f;
        if (t >= off) { v1 = sh1[t - off]; v2 = sh2[t - off]; }
        __syncthreads();
        sh1[t] += v1;
        sh2[t] += v2;
        __syncthreads();
    }
    const float pre1 = (t > 0) ? sh1[t - 1] : 0.f;
    const float pre2 = (t > 0) ? sh2[t - 1] : 0.f;
#pragma unroll
    for (int k = 0; k < RPT; ++k) {
        int r = r0 + k;
        if (r < NROWS) {
            float a = pre1 + cs1[k];   // cumsum of s1 -> lw1 = -a
            float b = pre2 + cs2[k];   // cumsum of s2 -> lw2 = -b
            // w1_bar = exp(-a)/(exp(-a)+exp(-b)) = 1/(1+exp(a-b))
            float e = expf(a - b);
            float inv = 1.0f / (1.0f + e);
            w1bo[r] = inv;
            w2bo[r] = e * inv;
        }
    }
}

// ---------------------------------------------------------------------------
// Kernel C: out[i][j] = f1[i]*w1b[j] + f2[i]*w2b[j]   (256 MB streaming write)
// ---------------------------------------------------------------------------
__global__ __launch_bounds__(256)
void anfis_out(const float* __restrict__ f1, const float* __restrict__ f2,
               const float* __restrict__ w1b, const float* __restrict__ w2b,
               float* __restrict__ out) {
    const int j4 = blockIdx.x * 256 + threadIdx.x;  // float4 column index
    if (j4 >= NCOL4) return;
    const int i = blockIdx.y;
    const float a = f1[i];
    const float b = f2[i];
    const float4 u = ((const float4*)w1b)[j4];
    const float4 v = ((const float4*)w2b)[j4];
    float4 o;
    o.x = a * u.x + b * v.x;
    o.y = a * u.y + b * v.y;
    o.z = a * u.z + b * v.z;
    o.w = a * u.w + b * v.w;
    ((float4*)out)[(size_t)i * NCOL4 + j4] = o;
}

// ---------------------------------------------------------------------------
extern "C" void kernel_launch(void* const* d_in, const int* in_sizes, int n_in,
                              void* d_out, int out_size, void* d_ws, size_t ws_size,
                              hipStream_t stream) {
    const float* x     = (const float*)d_in[0];
    const float* a1    = (const float*)d_in[1];
    const float* c1    = (const float*)d_in[2];
    const float* a2    = (const float*)d_in[3];
    const float* c2    = (const float*)d_in[4];
    const float* w_fc1 = (const float*)d_in[5];
    const float* b_fc1 = (const float*)d_in[6];
    const float* w_fc2 = (const float*)d_in[7];
    const float* b_fc2 = (const float*)d_in[8];
    float* out = (float*)d_out;

    float* ws  = (float*)d_ws;   // 48000 floats = 192 KB used
    float* s1  = ws;
    float* s2  = ws + 8000;
    float* f1  = ws + 16000;
    float* f2  = ws + 24000;
    float* w1b = ws + 32000;
    float* w2b = ws + 40000;

    anfis_rows<<<32, 256, 0, stream>>>(x, a1, c1, a2, c2,
                                       w_fc1, b_fc1, w_fc2, b_fc2,
                                       s1, s2, f1, f2);
    anfis_scan<<<1, SCAN_T, 0, stream>>>(s1, s2, w1b, w2b);
    anfis_out<<<dim3((NCOL4 + 255) / 256, NROWS), 256, 0, stream>>>(f1, f2, w1b, w2b, out);
}